// Round 8
// baseline (834.553 us; speedup 1.0000x reference)
//
#include <hip/hip_runtime.h>
#include <math.h>

// B=2, S=2048, E=2048, H=16, D=128; qkv width = 2304.
// d_in: 0=hidden(f32) 1=mask(causal, ignored) 2=c_attn_w(f32 E,2304) 3=c_attn_b 4=c_proj_w(f32 E,E) 5=c_proj_b

typedef __attribute__((ext_vector_type(8))) short short8;
typedef __attribute__((ext_vector_type(8))) __bf16 bf16x8;
typedef __attribute__((ext_vector_type(4))) float floatx4;
typedef __attribute__((ext_vector_type(4))) unsigned short ushort4v;
typedef unsigned short ushort;

__device__ __forceinline__ ushort f2bf(float f) {
    unsigned u = __builtin_bit_cast(unsigned, f);
    u += 0x7fffu + ((u >> 16) & 1u);
    return (ushort)(u >> 16);
}
__device__ __forceinline__ unsigned pk2(float a, float b) {
    return (unsigned)f2bf(a) | ((unsigned)f2bf(b) << 16);
}

template <typename V>
__device__ __forceinline__ auto mfma_try(V a, V b, floatx4 c, int)
    -> decltype(__builtin_amdgcn_mfma_f32_16x16x32_bf16(a, b, c, 0, 0, 0)) {
    return __builtin_amdgcn_mfma_f32_16x16x32_bf16(a, b, c, 0, 0, 0);
}
template <typename V>
__device__ __forceinline__ floatx4 mfma_try(V a, V b, floatx4 c, long) {
    return __builtin_amdgcn_mfma_f32_16x16x32_bf16(
        __builtin_bit_cast(bf16x8, a), __builtin_bit_cast(bf16x8, b), c, 0, 0, 0);
}
__device__ __forceinline__ floatx4 mfma_bf16(short8 a, short8 b, floatx4 c) {
    return mfma_try(a, b, c, 0);
}

__device__ __forceinline__ void gld_lds16(const ushort* g, ushort* l) {
    __builtin_amdgcn_global_load_lds(
        (const __attribute__((address_space(1))) unsigned*)(const void*)g,
        (__attribute__((address_space(3))) unsigned*)(void*)l, 16, 0, 0);
}

// ---------------- elementwise f32 -> bf16 ----------------
__global__ __launch_bounds__(256) void convert_bf16(const float* __restrict__ X,
                                                    ushort* __restrict__ Y, int n4) {
    int i = blockIdx.x * 256 + threadIdx.x;
    if (i >= n4) return;
    float4 v = ((const float4*)X)[i];
    ushort4v o = {f2bf(v.x), f2bf(v.y), f2bf(v.z), f2bf(v.w)};
    *(ushort4v*)&Y[(size_t)i * 4] = o;
}

// ---------------- W[K][N] f32 -> WT[N][K] bf16 (64x64 tiles) ----------------
__global__ __launch_bounds__(256) void transpose_convert(const float* __restrict__ W,
                                                         ushort* __restrict__ WT,
                                                         int K, int N) {
    __shared__ ushort T[64][68];
    const int tid = threadIdx.x;
    const int n0 = blockIdx.x * 64, k0 = blockIdx.y * 64;
    #pragma unroll
    for (int i = 0; i < 4; ++i) {
        int k = (tid >> 4) + i * 16, n = (tid & 15) * 4;
        float4 v = *(const float4*)&W[(size_t)(k0 + k) * N + n0 + n];
        T[n + 0][k] = f2bf(v.x); T[n + 1][k] = f2bf(v.y);
        T[n + 2][k] = f2bf(v.z); T[n + 3][k] = f2bf(v.w);
    }
    __syncthreads();
    #pragma unroll
    for (int i = 0; i < 4; ++i) {
        int idx = tid + i * 256;
        int n = idx >> 4, c4 = idx & 15;
        *(ushort4v*)&WT[(size_t)(n0 + n) * K + k0 + c4 * 4] =
            *(const ushort4v*)&T[n][c4 * 4];
    }
}

// ---------------- V slice of qkv -> VTg[b][d][s] (bf16 transpose) -----------
__global__ __launch_bounds__(256) void v_transpose(const ushort* __restrict__ qkv,
                                                   ushort* __restrict__ VTg) {
    __shared__ ushort T[64 * 72];                // [d][s] padded
    const int tid = threadIdx.x;
    const int s0 = blockIdx.x * 64, d0 = blockIdx.y * 64, b = blockIdx.z;
    const size_t bS = (size_t)b * 2048;
    #pragma unroll
    for (int i = 0; i < 2; ++i) {
        int idx = tid + i * 256;                 // 0..511
        int s = idx >> 3, d8 = idx & 7;
        short8 v = *(const short8*)&qkv[(bS + s0 + s) * 2304 + 2176 + d0 + d8 * 8];
        #pragma unroll
        for (int j = 0; j < 8; ++j)
            T[(d8 * 8 + j) * 72 + s] = (ushort)v[j];
    }
    __syncthreads();
    #pragma unroll
    for (int i = 0; i < 2; ++i) {
        int idx = tid + i * 256;
        int d = idx >> 3, s8 = idx & 7;
        *(short8*)&VTg[((size_t)b * 128 + d0 + d) * 2048 + s0 + s8 * 8] =
            *(const short8*)&T[d * 72 + s8 * 8];
    }
}

// ---------------- m97-style GEMM: C = A @ BT^T + bias ----------------------
template <int MODE>
__global__ __launch_bounds__(256) void gemm_m97(
    const ushort* __restrict__ A, const ushort* __restrict__ BT,
    const float* __restrict__ bias, void* __restrict__ C, int M, int N, int K)
{
    __shared__ ushort As[8192];
    __shared__ ushort Bs[8192];
    const int tid = threadIdx.x, lane = tid & 63, wid = tid >> 6;
    const int wr = wid >> 1, wc = wid & 1;
    const int lg = lane >> 4, li = lane & 15;
    const int m0 = blockIdx.y * 128, n0 = blockIdx.x * 128;
    const int srow = lane >> 3;
    const int sphys = (lane & 7) * 16;
    floatx4 acc[4][4] = {};

    for (int k0 = 0; k0 < K; k0 += 64) {
        __syncthreads();
        #pragma unroll
        for (int i = 0; i < 4; ++i) {
            const int c = wid * 4 + i;
            const int row = c * 8 + srow;
            const int lin = sphys ^ ((row & 7) << 4);
            gld_lds16(&A[(size_t)(m0 + row) * K + k0 + (lin >> 1)], &As[c * 512]);
            gld_lds16(&BT[(size_t)(n0 + row) * K + k0 + (lin >> 1)], &Bs[c * 512]);
        }
        __syncthreads();
        #pragma unroll
        for (int kk = 0; kk < 2; ++kk) {
            short8 af[4], bfv[4];
            const int pb = (kk * 64 + lg * 16) ^ ((li & 7) << 4);
            #pragma unroll
            for (int m = 0; m < 4; ++m)
                af[m] = *(const short8*)&As[(wr * 64 + m * 16 + li) * 64 + (pb >> 1)];
            #pragma unroll
            for (int n = 0; n < 4; ++n)
                bfv[n] = *(const short8*)&Bs[(wc * 64 + n * 16 + li) * 64 + (pb >> 1)];
            #pragma unroll
            for (int m = 0; m < 4; ++m)
                #pragma unroll
                for (int n = 0; n < 4; ++n)
                    acc[m][n] = mfma_bf16(af[m], bfv[n], acc[m][n]);
        }
    }

    #pragma unroll
    for (int m = 0; m < 4; ++m) {
        #pragma unroll
        for (int n = 0; n < 4; ++n) {
            const int col = n0 + wc * 64 + n * 16 + li;
            const float bv = bias[col];
            #pragma unroll
            for (int r = 0; r < 4; ++r) {
                const int row = m0 + wr * 64 + m * 16 + lg * 4 + r;
                float v = acc[m][n][r] + bv;
                if constexpr (MODE == 0) {
                    if (col < 2048) v *= 0.08838834764831845f;  // 1/sqrt(128) on Q
                    ((ushort*)C)[(size_t)row * N + col] = f2bf(v);
                } else {
                    ((float*)C)[(size_t)row * N + col] = v;
                }
            }
        }
    }
}

// ---------------- MQA flash attention v8 -----------------------------------
// r7 dual-set design with ALL lambdas removed from the kernel (r2/r7 showed
// array-by-reference lambdas demote accumulators to scratch). Explicitly
// duplicated softmax/epilogue, all-static indexing.
__global__ __launch_bounds__(256, 3) void attn_kernel(
    const ushort* __restrict__ qkv,   // [B*S][2304] bf16; Q pre-scaled
    const ushort* __restrict__ VTg,   // [B][128][2048] bf16 (V transposed)
    ushort* __restrict__ out)         // [B*S][2048] bf16
{
    constexpr int S = 2048, Dh = 128, QKV = 2304, E = 2048;
    __shared__ ushort lds[24576];               // 48.0 KB -> 3 blocks/CU
    ushort* Ks = lds;                           // [64][128], granule^=(key&7)
    ushort* VT = lds + 8192;                    // [128][64], granule^=(d&7)
    ushort* Ps = lds + 16384;                   // [4][2][16][64], granule^=(q&7)

    const int tid = threadIdx.x, lane = tid & 63, wid = tid >> 6;
    const int lg = lane >> 4, li = lane & 15;
    const int x = blockIdx.x;
    const int st = (x & 1) ? (x >> 1) : (15 - (x >> 1));   // balanced pairing
    const int h = blockIdx.y, b = blockIdx.z;
    const size_t bS = (size_t)b * S;
    const int qA = st * 128 + wid * 16;          // set A = q-tile 2st
    const int qB = qA + 64;                      // set B = q-tile 2st+1

    // Q fragments (B-operand: col=q=li, k=d)
    short8 qfA[4], qfB[4];
    #pragma unroll
    for (int dc = 0; dc < 4; ++dc) {
        qfA[dc] = *(const short8*)&qkv[(bS + qA + li) * QKV + h * Dh + dc * 32 + lg * 8];
        qfB[dc] = *(const short8*)&qkv[(bS + qB + li) * QKV + h * Dh + dc * 32 + lg * 8];
    }

    floatx4 oA[8] = {}, oB[8] = {};
    float mA = -1e30f, lA = 0.f, mB = -1e30f, lB = 0.f;
    const int ntiles = 2 * st + 2;

    for (int t = 0; t < ntiles; ++t) {
        const int k0 = t * 64;
        __syncthreads();                         // prev compute done, LDS reusable
        // --- stage K: linear dest, inverse-swizzled source ---
        #pragma unroll
        for (int i = 0; i < 4; ++i) {
            const int idx = tid + i * 256;       // granule 0..1023
            const int row = idx >> 4, g = idx & 15;
            const int src = (g * 16) ^ ((row & 7) << 4);     // byte in 256B row
            gld_lds16(&qkv[(bS + k0 + row) * QKV + E + (src >> 1)],
                      &Ks[(i * 256 + wid * 64) * 8]);
        }
        // --- stage V from VTg: linear dest, inverse-swizzled source ---
        #pragma unroll
        for (int i = 0; i < 4; ++i) {
            const int idx = tid + i * 256;       // granule 0..1023
            const int d = idx >> 3, kg = idx & 7;
            gld_lds16(&VTg[((size_t)b * 128 + d) * 2048 + k0 + ((kg ^ (d & 7)) << 3)],
                      &VT[(i * 256 + wid * 64) * 8]);
        }
        __syncthreads();                         // drain + stage visible

        const bool actA = (t <= 2 * st);         // block-uniform

        // --- QK^T (swapped): each kf read feeds both sets ---
        floatx4 sA[4] = {{0,0,0,0},{0,0,0,0},{0,0,0,0},{0,0,0,0}};
        floatx4 sB[4] = {{0,0,0,0},{0,0,0,0},{0,0,0,0},{0,0,0,0}};
        #pragma unroll
        for (int dc = 0; dc < 4; ++dc) {
            #pragma unroll
            for (int kb = 0; kb < 4; ++kb) {
                short8 kf = *(const short8*)&Ks[(kb * 16 + li) * 128 +
                                                (((dc * 4 + lg) ^ (li & 7)) << 3)];
                if (actA) sA[kb] = mfma_bf16(kf, qfA[dc], sA[kb]);
                sB[kb] = mfma_bf16(kf, qfB[dc], sB[kb]);
            }
        }
        // --- causal masks (block-uniform branches; local form) ---
        if (actA && t == 2 * st) {
            #pragma unroll
            for (int kb = 0; kb < 4; ++kb)
                #pragma unroll
                for (int r = 0; r < 4; ++r)
                    if (kb * 16 + lg * 4 + r > wid * 16 + li) sA[kb][r] = -1e30f;
        }
        if (t == 2 * st + 1) {
            #pragma unroll
            for (int kb = 0; kb < 4; ++kb)
                #pragma unroll
                for (int r = 0; r < 4; ++r)
                    if (kb * 16 + lg * 4 + r > wid * 16 + li) sB[kb][r] = -1e30f;
        }

        // ---------------- softmax set A (explicit, no lambda) ----------------
        if (actA) {
            float mt = fmaxf(fmaxf(fmaxf(sA[0][0], sA[0][1]), fmaxf(sA[0][2], sA[0][3])),
                             fmaxf(fmaxf(sA[1][0], sA[1][1]), fmaxf(sA[1][2], sA[1][3])));
            mt = fmaxf(mt, fmaxf(fmaxf(fmaxf(sA[2][0], sA[2][1]), fmaxf(sA[2][2], sA[2][3])),
                                 fmaxf(fmaxf(sA[3][0], sA[3][1]), fmaxf(sA[3][2], sA[3][3]))));
            mt = fmaxf(mt, __shfl_xor(mt, 16));
            mt = fmaxf(mt, __shfl_xor(mt, 32));
            const float mn = fmaxf(mA, mt);
            const float sc = __expf(mA - mn);
            mA = mn;
            float rs = 0.f;
            #pragma unroll
            for (int kb = 0; kb < 4; ++kb)
                #pragma unroll
                for (int r = 0; r < 4; ++r) {
                    float p = __expf(sA[kb][r] - mn);
                    sA[kb][r] = p; rs += p;
                }
            rs += __shfl_xor(rs, 16);
            rs += __shfl_xor(rs, 32);
            lA = lA * sc + rs;
            #pragma unroll
            for (int db = 0; db < 8; ++db) oA[db] *= sc;
            #pragma unroll
            for (int kb = 0; kb < 4; ++kb) {
                const int g = kb * 2 + (lg >> 1);
                const int sw = ((g ^ (li & 7)) << 3) + ((lg & 1) * 4);
                *(unsigned*)&Ps[wid * 2048 + li * 64 + sw]     = pk2(sA[kb][0], sA[kb][1]);
                *(unsigned*)&Ps[wid * 2048 + li * 64 + sw + 2] = pk2(sA[kb][2], sA[kb][3]);
            }
        }
        // ---------------- softmax set B (explicit, no lambda) ----------------
        {
            float mt = fmaxf(fmaxf(fmaxf(sB[0][0], sB[0][1]), fmaxf(sB[0][2], sB[0][3])),
                             fmaxf(fmaxf(sB[1][0], sB[1][1]), fmaxf(sB[1][2], sB[1][3])));
            mt = fmaxf(mt, fmaxf(fmaxf(fmaxf(sB[2][0], sB[2][1]), fmaxf(sB[2][2], sB[2][3])),
                                 fmaxf(fmaxf(sB[3][0], sB[3][1]), fmaxf(sB[3][2], sB[3][3]))));
            mt = fmaxf(mt, __shfl_xor(mt, 16));
            mt = fmaxf(mt, __shfl_xor(mt, 32));
            const float mn = fmaxf(mB, mt);
            const float sc = __expf(mB - mn);
            mB = mn;
            float rs = 0.f;
            #pragma unroll
            for (int kb = 0; kb < 4; ++kb)
                #pragma unroll
                for (int r = 0; r < 4; ++r) {
                    float p = __expf(sB[kb][r] - mn);
                    sB[kb][r] = p; rs += p;
                }
            rs += __shfl_xor(rs, 16);
            rs += __shfl_xor(rs, 32);
            lB = lB * sc + rs;
            #pragma unroll
            for (int db = 0; db < 8; ++db) oB[db] *= sc;
            #pragma unroll
            for (int kb = 0; kb < 4; ++kb) {
                const int g = kb * 2 + (lg >> 1);
                const int sw = ((g ^ (li & 7)) << 3) + ((lg & 1) * 4);
                *(unsigned*)&Ps[wid * 2048 + 1024 + li * 64 + sw]     = pk2(sB[kb][0], sB[kb][1]);
                *(unsigned*)&Ps[wid * 2048 + 1024 + li * 64 + sw + 2] = pk2(sB[kb][2], sB[kb][3]);
            }
        }

        // --- PV: each vt read feeds both sets ---
        #pragma unroll
        for (int kc = 0; kc < 2; ++kc) {
            short8 pA = {}, pB;
            if (actA) pA = *(const short8*)&Ps[wid * 2048 + li * 64 +
                                               (((kc * 4 + lg) ^ (li & 7)) << 3)];
            pB = *(const short8*)&Ps[wid * 2048 + 1024 + li * 64 +
                                     (((kc * 4 + lg) ^ (li & 7)) << 3)];
            #pragma unroll
            for (int db = 0; db < 8; ++db) {
                short8 vt = *(const short8*)&VT[(db * 16 + li) * 64 +
                                                (((kc * 4 + lg) ^ (li & 7)) << 3)];
                if (actA) oA[db] = mfma_bf16(vt, pA, oA[db]);
                oB[db] = mfma_bf16(vt, pB, oB[db]);
            }
        }
    }

    // --- epilogue (explicit for each set): normalize, LDS bounce, store ---
    __syncthreads();                             // all waves done reading Ks/VT/Ps
    ushort* Pw = lds + wid * 2176;               // 16 x 136 per wave
    {
        const float inv = 1.0f / lA;
        #pragma unroll
        for (int db = 0; db < 8; ++db) {
            *(unsigned*)&Pw[li * 136 + db * 16 + lg * 4]     = pk2(oA[db][0] * inv, oA[db][1] * inv);
            *(unsigned*)&Pw[li * 136 + db * 16 + lg * 4 + 2] = pk2(oA[db][2] * inv, oA[db][3] * inv);
        }
        #pragma unroll
        for (int i = 0; i < 4; ++i) {
            const int q = lane >> 2, d8 = (lane & 3) + i * 4;
            short8 vv = *(const short8*)&Pw[q * 136 + d8 * 8];
            *(short8*)&out[(bS + qA + q) * E + h * Dh + d8 * 8] = vv;
        }
    }
    {
        const float inv = 1.0f / lB;
        #pragma unroll
        for (int db = 0; db < 8; ++db) {
            *(unsigned*)&Pw[li * 136 + db * 16 + lg * 4]     = pk2(oB[db][0] * inv, oB[db][1] * inv);
            *(unsigned*)&Pw[li * 136 + db * 16 + lg * 4 + 2] = pk2(oB[db][2] * inv, oB[db][3] * inv);
        }
        #pragma unroll
        for (int i = 0; i < 4; ++i) {
            const int q = lane >> 2, d8 = (lane & 3) + i * 4;
            short8 vv = *(const short8*)&Pw[q * 136 + d8 * 8];
            *(short8*)&out[(bS + qB + q) * E + h * Dh + d8 * 8] = vv;
        }
    }
}

extern "C" void kernel_launch(void* const* d_in, const int* in_sizes, int n_in,
                              void* d_out, int out_size, void* d_ws, size_t ws_size,
                              hipStream_t stream) {
    (void)in_sizes; (void)n_in; (void)out_size; (void)ws_size;
    const float* hidden   = (const float*)d_in[0];
    const float* c_attn_w = (const float*)d_in[2];
    const float* c_attn_b = (const float*)d_in[3];
    const float* c_proj_w = (const float*)d_in[4];
    const float* c_proj_b = (const float*)d_in[5];
    float* outp = (float*)d_out;

    char* ws = (char*)d_ws;
    ushort* hbf  = (ushort*)ws;                                    // 4096x2048 bf16 -> later attn buf
    ushort* W1T  = (ushort*)(ws + (size_t)16777216);               // 2304x2048 bf16
    ushort* W2T  = (ushort*)(ws + (size_t)16777216 + 9437184);     // 2048x2048 bf16
    ushort* qkv  = (ushort*)(ws + (size_t)16777216 + 9437184 + 8388608);  // 4096x2304 bf16
    ushort* VTg  = (ushort*)(ws + (size_t)16777216 + 9437184 + 8388608 + 18874368); // 2x128x2048
    ushort* attn = hbf;   // reuse: hidden_bf16 dead after GEMM1

    convert_bf16<<<8192, 256, 0, stream>>>(hidden, hbf, 4096 * 2048 / 4);
    transpose_convert<<<dim3(36, 32), 256, 0, stream>>>(c_attn_w, W1T, 2048, 2304);
    transpose_convert<<<dim3(32, 32), 256, 0, stream>>>(c_proj_w, W2T, 2048, 2048);

    gemm_m97<0><<<dim3(18, 32), 256, 0, stream>>>(hbf, W1T, c_attn_b, qkv, 4096, 2304, 2048);
    v_transpose<<<dim3(32, 2, 2), 256, 0, stream>>>(qkv, VTg);
    attn_kernel<<<dim3(16, 16, 2), 256, 0, stream>>>(qkv, VTg, attn);
    gemm_m97<1><<<dim3(16, 32), 256, 0, stream>>>(attn, W2T, c_proj_b, outp, 4096, 2048, 2048);
}

// Round 9
// 239.707 us; speedup vs baseline: 3.4816x; 3.4816x over previous
//
#include <hip/hip_runtime.h>
#include <math.h>

// B=2, S=2048, E=2048, H=16, D=128; qkv width = 2304.
// d_in: 0=hidden(f32) 1=mask(causal, ignored) 2=c_attn_w(f32 E,2304) 3=c_attn_b 4=c_proj_w(f32 E,E) 5=c_proj_b

typedef __attribute__((ext_vector_type(8))) short short8;
typedef __attribute__((ext_vector_type(8))) __bf16 bf16x8;
typedef __attribute__((ext_vector_type(4))) float floatx4;
typedef __attribute__((ext_vector_type(4))) unsigned short ushort4v;
typedef unsigned short ushort;

__device__ __forceinline__ ushort f2bf(float f) {
    unsigned u = __builtin_bit_cast(unsigned, f);
    u += 0x7fffu + ((u >> 16) & 1u);
    return (ushort)(u >> 16);
}
__device__ __forceinline__ unsigned pk2(float a, float b) {
    return (unsigned)f2bf(a) | ((unsigned)f2bf(b) << 16);
}

template <typename V>
__device__ __forceinline__ auto mfma_try(V a, V b, floatx4 c, int)
    -> decltype(__builtin_amdgcn_mfma_f32_16x16x32_bf16(a, b, c, 0, 0, 0)) {
    return __builtin_amdgcn_mfma_f32_16x16x32_bf16(a, b, c, 0, 0, 0);
}
template <typename V>
__device__ __forceinline__ floatx4 mfma_try(V a, V b, floatx4 c, long) {
    return __builtin_amdgcn_mfma_f32_16x16x32_bf16(
        __builtin_bit_cast(bf16x8, a), __builtin_bit_cast(bf16x8, b), c, 0, 0, 0);
}
__device__ __forceinline__ floatx4 mfma_bf16(short8 a, short8 b, floatx4 c) {
    return mfma_try(a, b, c, 0);
}

__device__ __forceinline__ void gld_lds16(const ushort* g, ushort* l) {
    __builtin_amdgcn_global_load_lds(
        (const __attribute__((address_space(1))) unsigned*)(const void*)g,
        (__attribute__((address_space(3))) unsigned*)(void*)l, 16, 0, 0);
}

// ---------------- elementwise f32 -> bf16 ----------------
__global__ __launch_bounds__(256) void convert_bf16(const float* __restrict__ X,
                                                    ushort* __restrict__ Y, int n4) {
    int i = blockIdx.x * 256 + threadIdx.x;
    if (i >= n4) return;
    float4 v = ((const float4*)X)[i];
    ushort4v o = {f2bf(v.x), f2bf(v.y), f2bf(v.z), f2bf(v.w)};
    *(ushort4v*)&Y[(size_t)i * 4] = o;
}

// ---------------- W[K][N] f32 -> WT[N][K] bf16 (64x64 tiles) ----------------
__global__ __launch_bounds__(256) void transpose_convert(const float* __restrict__ W,
                                                         ushort* __restrict__ WT,
                                                         int K, int N) {
    __shared__ ushort T[64][68];
    const int tid = threadIdx.x;
    const int n0 = blockIdx.x * 64, k0 = blockIdx.y * 64;
    #pragma unroll
    for (int i = 0; i < 4; ++i) {
        int k = (tid >> 4) + i * 16, n = (tid & 15) * 4;
        float4 v = *(const float4*)&W[(size_t)(k0 + k) * N + n0 + n];
        T[n + 0][k] = f2bf(v.x); T[n + 1][k] = f2bf(v.y);
        T[n + 2][k] = f2bf(v.z); T[n + 3][k] = f2bf(v.w);
    }
    __syncthreads();
    #pragma unroll
    for (int i = 0; i < 4; ++i) {
        int idx = tid + i * 256;
        int n = idx >> 4, c4 = idx & 15;
        *(ushort4v*)&WT[(size_t)(n0 + n) * K + k0 + c4 * 4] =
            *(const ushort4v*)&T[n][c4 * 4];
    }
}

// ---------------- V slice of qkv -> VTg[b][d][s] (bf16 transpose) -----------
__global__ __launch_bounds__(256) void v_transpose(const ushort* __restrict__ qkv,
                                                   ushort* __restrict__ VTg) {
    __shared__ ushort T[64 * 72];                // [d][s] padded
    const int tid = threadIdx.x;
    const int s0 = blockIdx.x * 64, d0 = blockIdx.y * 64, b = blockIdx.z;
    const size_t bS = (size_t)b * 2048;
    #pragma unroll
    for (int i = 0; i < 2; ++i) {
        int idx = tid + i * 256;                 // 0..511
        int s = idx >> 3, d8 = idx & 7;
        short8 v = *(const short8*)&qkv[(bS + s0 + s) * 2304 + 2176 + d0 + d8 * 8];
        #pragma unroll
        for (int j = 0; j < 8; ++j)
            T[(d8 * 8 + j) * 72 + s] = (ushort)v[j];
    }
    __syncthreads();
    #pragma unroll
    for (int i = 0; i < 2; ++i) {
        int idx = tid + i * 256;
        int d = idx >> 3, s8 = idx & 7;
        *(short8*)&VTg[((size_t)b * 128 + d0 + d) * 2048 + s0 + s8 * 8] =
            *(const short8*)&T[d * 72 + s8 * 8];
    }
}

// ---------------- m97-style GEMM: C = A @ BT^T + bias ----------------------
template <int MODE>
__global__ __launch_bounds__(256) void gemm_m97(
    const ushort* __restrict__ A, const ushort* __restrict__ BT,
    const float* __restrict__ bias, void* __restrict__ C, int M, int N, int K)
{
    __shared__ ushort As[8192];
    __shared__ ushort Bs[8192];
    const int tid = threadIdx.x, lane = tid & 63, wid = tid >> 6;
    const int wr = wid >> 1, wc = wid & 1;
    const int lg = lane >> 4, li = lane & 15;
    const int m0 = blockIdx.y * 128, n0 = blockIdx.x * 128;
    const int srow = lane >> 3;
    const int sphys = (lane & 7) * 16;
    floatx4 acc[4][4] = {};

    for (int k0 = 0; k0 < K; k0 += 64) {
        __syncthreads();
        #pragma unroll
        for (int i = 0; i < 4; ++i) {
            const int c = wid * 4 + i;
            const int row = c * 8 + srow;
            const int lin = sphys ^ ((row & 7) << 4);
            gld_lds16(&A[(size_t)(m0 + row) * K + k0 + (lin >> 1)], &As[c * 512]);
            gld_lds16(&BT[(size_t)(n0 + row) * K + k0 + (lin >> 1)], &Bs[c * 512]);
        }
        __syncthreads();
        #pragma unroll
        for (int kk = 0; kk < 2; ++kk) {
            short8 af[4], bfv[4];
            const int pb = (kk * 64 + lg * 16) ^ ((li & 7) << 4);
            #pragma unroll
            for (int m = 0; m < 4; ++m)
                af[m] = *(const short8*)&As[(wr * 64 + m * 16 + li) * 64 + (pb >> 1)];
            #pragma unroll
            for (int n = 0; n < 4; ++n)
                bfv[n] = *(const short8*)&Bs[(wc * 64 + n * 16 + li) * 64 + (pb >> 1)];
            #pragma unroll
            for (int m = 0; m < 4; ++m)
                #pragma unroll
                for (int n = 0; n < 4; ++n)
                    acc[m][n] = mfma_bf16(af[m], bfv[n], acc[m][n]);
        }
    }

    #pragma unroll
    for (int m = 0; m < 4; ++m) {
        #pragma unroll
        for (int n = 0; n < 4; ++n) {
            const int col = n0 + wc * 64 + n * 16 + li;
            const float bv = bias[col];
            #pragma unroll
            for (int r = 0; r < 4; ++r) {
                const int row = m0 + wr * 64 + m * 16 + lg * 4 + r;
                float v = acc[m][n][r] + bv;
                if constexpr (MODE == 0) {
                    if (col < 2048) v *= 0.08838834764831845f;  // 1/sqrt(128) on Q
                    ((ushort*)C)[(size_t)row * N + col] = f2bf(v);
                } else {
                    ((float*)C)[(size_t)row * N + col] = v;
                }
            }
        }
    }
}

// ---------------- MQA flash attention v9 -----------------------------------
// Dual-set with launch_bounds(256,2): 256-VGPR cap fits the ~160-reg live set
// (r7/r8's (256,3)=168 cap demoted it to scratch). actA guards removed: set A
// is force-masked on the final tile (contributes exactly 0), unconditional
// dataflow.
__global__ __launch_bounds__(256, 2) void attn_kernel(
    const ushort* __restrict__ qkv,   // [B*S][2304] bf16; Q pre-scaled
    const ushort* __restrict__ VTg,   // [B][128][2048] bf16 (V transposed)
    ushort* __restrict__ out)         // [B*S][2048] bf16
{
    constexpr int S = 2048, Dh = 128, QKV = 2304, E = 2048;
    __shared__ ushort lds[24576];               // 48.0 KB -> 2 blocks/CU
    ushort* Ks = lds;                           // [64][128], granule^=(key&7)
    ushort* VT = lds + 8192;                    // [128][64], granule^=(d&7)
    ushort* Ps = lds + 16384;                   // [4][2][16][64], granule^=(q&7)

    const int tid = threadIdx.x, lane = tid & 63, wid = tid >> 6;
    const int lg = lane >> 4, li = lane & 15;
    const int x = blockIdx.x;
    const int st = (x & 1) ? (x >> 1) : (15 - (x >> 1));   // balanced pairing
    const int h = blockIdx.y, b = blockIdx.z;
    const size_t bS = (size_t)b * S;
    const int qA = st * 128 + wid * 16;          // set A = q-tile 2st
    const int qB = qA + 64;                      // set B = q-tile 2st+1

    // Q fragments (B-operand: col=q=li, k=d)
    short8 qfA[4], qfB[4];
    #pragma unroll
    for (int dc = 0; dc < 4; ++dc) {
        qfA[dc] = *(const short8*)&qkv[(bS + qA + li) * QKV + h * Dh + dc * 32 + lg * 8];
        qfB[dc] = *(const short8*)&qkv[(bS + qB + li) * QKV + h * Dh + dc * 32 + lg * 8];
    }

    floatx4 oA[8] = {}, oB[8] = {};
    float mA = -1e30f, lA = 0.f, mB = -1e30f, lB = 0.f;
    const int ntiles = 2 * st + 2;

    for (int t = 0; t < ntiles; ++t) {
        const int k0 = t * 64;
        __syncthreads();                         // prev compute done, LDS reusable
        // --- stage K: linear dest, inverse-swizzled source ---
        #pragma unroll
        for (int i = 0; i < 4; ++i) {
            const int idx = tid + i * 256;       // granule 0..1023
            const int row = idx >> 4, g = idx & 15;
            const int src = (g * 16) ^ ((row & 7) << 4);     // byte in 256B row
            gld_lds16(&qkv[(bS + k0 + row) * QKV + E + (src >> 1)],
                      &Ks[(i * 256 + wid * 64) * 8]);
        }
        // --- stage V from VTg: linear dest, inverse-swizzled source ---
        #pragma unroll
        for (int i = 0; i < 4; ++i) {
            const int idx = tid + i * 256;       // granule 0..1023
            const int d = idx >> 3, kg = idx & 7;
            gld_lds16(&VTg[((size_t)b * 128 + d) * 2048 + k0 + ((kg ^ (d & 7)) << 3)],
                      &VT[(i * 256 + wid * 64) * 8]);
        }
        __syncthreads();                         // drain + stage visible

        // --- QK^T (swapped): each kf read feeds both sets ---
        floatx4 sA[4] = {{0,0,0,0},{0,0,0,0},{0,0,0,0},{0,0,0,0}};
        floatx4 sB[4] = {{0,0,0,0},{0,0,0,0},{0,0,0,0},{0,0,0,0}};
        #pragma unroll
        for (int dc = 0; dc < 4; ++dc) {
            #pragma unroll
            for (int kb = 0; kb < 4; ++kb) {
                short8 kf = *(const short8*)&Ks[(kb * 16 + li) * 128 +
                                                (((dc * 4 + lg) ^ (li & 7)) << 3)];
                sA[kb] = mfma_bf16(kf, qfA[dc], sA[kb]);
                sB[kb] = mfma_bf16(kf, qfB[dc], sB[kb]);
            }
        }
        // --- causal masks (block-uniform branches) ---
        if (t == 2 * st) {                       // diagonal tile for set A
            #pragma unroll
            for (int kb = 0; kb < 4; ++kb)
                #pragma unroll
                for (int r = 0; r < 4; ++r)
                    if (kb * 16 + lg * 4 + r > wid * 16 + li) sA[kb][r] = -1e30f;
        }
        if (t == 2 * st + 1) {                   // last tile: A fully masked, B diagonal
            #pragma unroll
            for (int kb = 0; kb < 4; ++kb)
                #pragma unroll
                for (int r = 0; r < 4; ++r) {
                    sA[kb][r] = -1e30f;
                    if (kb * 16 + lg * 4 + r > wid * 16 + li) sB[kb][r] = -1e30f;
                }
        }

        // ---------------- softmax set A ----------------
        {
            float mt = fmaxf(fmaxf(fmaxf(sA[0][0], sA[0][1]), fmaxf(sA[0][2], sA[0][3])),
                             fmaxf(fmaxf(sA[1][0], sA[1][1]), fmaxf(sA[1][2], sA[1][3])));
            mt = fmaxf(mt, fmaxf(fmaxf(fmaxf(sA[2][0], sA[2][1]), fmaxf(sA[2][2], sA[2][3])),
                                 fmaxf(fmaxf(sA[3][0], sA[3][1]), fmaxf(sA[3][2], sA[3][3]))));
            mt = fmaxf(mt, __shfl_xor(mt, 16));
            mt = fmaxf(mt, __shfl_xor(mt, 32));
            const float mn = fmaxf(mA, mt);
            const float sc = __expf(mA - mn);
            mA = mn;
            float rs = 0.f;
            #pragma unroll
            for (int kb = 0; kb < 4; ++kb)
                #pragma unroll
                for (int r = 0; r < 4; ++r) {
                    float p = __expf(sA[kb][r] - mn);
                    sA[kb][r] = p; rs += p;
                }
            rs += __shfl_xor(rs, 16);
            rs += __shfl_xor(rs, 32);
            lA = lA * sc + rs;
            #pragma unroll
            for (int db = 0; db < 8; ++db) oA[db] *= sc;
            #pragma unroll
            for (int kb = 0; kb < 4; ++kb) {
                const int g = kb * 2 + (lg >> 1);
                const int sw = ((g ^ (li & 7)) << 3) + ((lg & 1) * 4);
                *(unsigned*)&Ps[wid * 2048 + li * 64 + sw]     = pk2(sA[kb][0], sA[kb][1]);
                *(unsigned*)&Ps[wid * 2048 + li * 64 + sw + 2] = pk2(sA[kb][2], sA[kb][3]);
            }
        }
        // ---------------- softmax set B ----------------
        {
            float mt = fmaxf(fmaxf(fmaxf(sB[0][0], sB[0][1]), fmaxf(sB[0][2], sB[0][3])),
                             fmaxf(fmaxf(sB[1][0], sB[1][1]), fmaxf(sB[1][2], sB[1][3])));
            mt = fmaxf(mt, fmaxf(fmaxf(fmaxf(sB[2][0], sB[2][1]), fmaxf(sB[2][2], sB[2][3])),
                                 fmaxf(fmaxf(sB[3][0], sB[3][1]), fmaxf(sB[3][2], sB[3][3]))));
            mt = fmaxf(mt, __shfl_xor(mt, 16));
            mt = fmaxf(mt, __shfl_xor(mt, 32));
            const float mn = fmaxf(mB, mt);
            const float sc = __expf(mB - mn);
            mB = mn;
            float rs = 0.f;
            #pragma unroll
            for (int kb = 0; kb < 4; ++kb)
                #pragma unroll
                for (int r = 0; r < 4; ++r) {
                    float p = __expf(sB[kb][r] - mn);
                    sB[kb][r] = p; rs += p;
                }
            rs += __shfl_xor(rs, 16);
            rs += __shfl_xor(rs, 32);
            lB = lB * sc + rs;
            #pragma unroll
            for (int db = 0; db < 8; ++db) oB[db] *= sc;
            #pragma unroll
            for (int kb = 0; kb < 4; ++kb) {
                const int g = kb * 2 + (lg >> 1);
                const int sw = ((g ^ (li & 7)) << 3) + ((lg & 1) * 4);
                *(unsigned*)&Ps[wid * 2048 + 1024 + li * 64 + sw]     = pk2(sB[kb][0], sB[kb][1]);
                *(unsigned*)&Ps[wid * 2048 + 1024 + li * 64 + sw + 2] = pk2(sB[kb][2], sB[kb][3]);
            }
        }

        // --- PV: each vt read feeds both sets ---
        #pragma unroll
        for (int kc = 0; kc < 2; ++kc) {
            short8 pA = *(const short8*)&Ps[wid * 2048 + li * 64 +
                                            (((kc * 4 + lg) ^ (li & 7)) << 3)];
            short8 pB = *(const short8*)&Ps[wid * 2048 + 1024 + li * 64 +
                                            (((kc * 4 + lg) ^ (li & 7)) << 3)];
            #pragma unroll
            for (int db = 0; db < 8; ++db) {
                short8 vt = *(const short8*)&VT[(db * 16 + li) * 64 +
                                                (((kc * 4 + lg) ^ (li & 7)) << 3)];
                oA[db] = mfma_bf16(vt, pA, oA[db]);
                oB[db] = mfma_bf16(vt, pB, oB[db]);
            }
        }
    }

    // --- epilogue (explicit for each set): normalize, LDS bounce, store ---
    __syncthreads();                             // all waves done reading Ks/VT/Ps
    ushort* Pw = lds + wid * 2176;               // 16 x 136 per wave
    {
        const float inv = 1.0f / lA;
        #pragma unroll
        for (int db = 0; db < 8; ++db) {
            *(unsigned*)&Pw[li * 136 + db * 16 + lg * 4]     = pk2(oA[db][0] * inv, oA[db][1] * inv);
            *(unsigned*)&Pw[li * 136 + db * 16 + lg * 4 + 2] = pk2(oA[db][2] * inv, oA[db][3] * inv);
        }
        #pragma unroll
        for (int i = 0; i < 4; ++i) {
            const int q = lane >> 2, d8 = (lane & 3) + i * 4;
            short8 vv = *(const short8*)&Pw[q * 136 + d8 * 8];
            *(short8*)&out[(bS + qA + q) * E + h * Dh + d8 * 8] = vv;
        }
    }
    {
        const float inv = 1.0f / lB;
        #pragma unroll
        for (int db = 0; db < 8; ++db) {
            *(unsigned*)&Pw[li * 136 + db * 16 + lg * 4]     = pk2(oB[db][0] * inv, oB[db][1] * inv);
            *(unsigned*)&Pw[li * 136 + db * 16 + lg * 4 + 2] = pk2(oB[db][2] * inv, oB[db][3] * inv);
        }
        #pragma unroll
        for (int i = 0; i < 4; ++i) {
            const int q = lane >> 2, d8 = (lane & 3) + i * 4;
            short8 vv = *(const short8*)&Pw[q * 136 + d8 * 8];
            *(short8*)&out[(bS + qB + q) * E + h * Dh + d8 * 8] = vv;
        }
    }
}

extern "C" void kernel_launch(void* const* d_in, const int* in_sizes, int n_in,
                              void* d_out, int out_size, void* d_ws, size_t ws_size,
                              hipStream_t stream) {
    (void)in_sizes; (void)n_in; (void)out_size; (void)ws_size;
    const float* hidden   = (const float*)d_in[0];
    const float* c_attn_w = (const float*)d_in[2];
    const float* c_attn_b = (const float*)d_in[3];
    const float* c_proj_w = (const float*)d_in[4];
    const float* c_proj_b = (const float*)d_in[5];
    float* outp = (float*)d_out;

    char* ws = (char*)d_ws;
    ushort* hbf  = (ushort*)ws;                                    // 4096x2048 bf16 -> later attn buf
    ushort* W1T  = (ushort*)(ws + (size_t)16777216);               // 2304x2048 bf16
    ushort* W2T  = (ushort*)(ws + (size_t)16777216 + 9437184);     // 2048x2048 bf16
    ushort* qkv  = (ushort*)(ws + (size_t)16777216 + 9437184 + 8388608);  // 4096x2304 bf16
    ushort* VTg  = (ushort*)(ws + (size_t)16777216 + 9437184 + 8388608 + 18874368); // 2x128x2048
    ushort* attn = hbf;   // reuse: hidden_bf16 dead after GEMM1

    convert_bf16<<<8192, 256, 0, stream>>>(hidden, hbf, 4096 * 2048 / 4);
    transpose_convert<<<dim3(36, 32), 256, 0, stream>>>(c_attn_w, W1T, 2048, 2304);
    transpose_convert<<<dim3(32, 32), 256, 0, stream>>>(c_proj_w, W2T, 2048, 2048);

    gemm_m97<0><<<dim3(18, 32), 256, 0, stream>>>(hbf, W1T, c_attn_b, qkv, 4096, 2304, 2048);
    v_transpose<<<dim3(32, 2, 2), 256, 0, stream>>>(qkv, VTg);
    attn_kernel<<<dim3(16, 16, 2), 256, 0, stream>>>(qkv, VTg, attn);
    gemm_m97<1><<<dim3(16, 32), 256, 0, stream>>>(attn, W2T, c_proj_b, outp, 4096, 2048, 2048);
}